// Round 4
// baseline (512.111 us; speedup 1.0000x reference)
//
#include <hip/hip_runtime.h>

// CliqueEncoder: N=1e6 rows, H=128, RBF=32, H2=64, NUM_TYPES=4.
// t,d in [0,4) -> only 16 distinct 128-float output rows.
// K1: build 16x128 LUT (8 KB) in d_ws.
// K2: block-tiled broadcast: LUT->LDS once/block, attr loaded once/row,
//     then pure store loop (ds_read_b128 + NON-TEMPORAL global_store_dwordx4).
// Theory under test: nt stores on the 512 MB write-once output stream
// bypass L2/L3 allocation — predicted FETCH_SIZE collapse if write-allocate
// was the 509-µs baseline's cost. nt loads on the read-once attr stream too.
// R3 fix: __builtin_nontemporal_load needs a clang ext_vector type, not
// HIP_vector_type<int,2> — use i32x2.

typedef float f32x4 __attribute__((ext_vector_type(4)));
typedef int   i32x2 __attribute__((ext_vector_type(2)));

#define HH 128
#define H2 64
#define RBF 32
#define MAX_DIST 20.0f
#define ROWS_PER_BLOCK 1024

__global__ void clique_build_lut(const float* __restrict__ emb_table,
                                 const float* __restrict__ W,
                                 const float* __restrict__ b,
                                 float* __restrict__ lut) {
    int combo = blockIdx.x;      // 0..15  (t*4 + d)
    int t = combo >> 2;
    int dval = combo & 3;
    int j = threadIdx.x;         // 0..63  (H2 column)
    float d = (float)dval;
    const float stdv = MAX_DIST / (float)(RBF - 1);   // centers[1]-centers[0]
    float acc = 0.0f;
#pragma unroll
    for (int k = 0; k < RBF; ++k) {
        float c = MAX_DIST * (float)k / (float)(RBF - 1);
        float diff = d - c;
        float basis = expf(-0.5f * diff * diff / (stdv * stdv));
        acc += basis * W[t * (RBF * H2) + k * H2 + j];
    }
    lut[combo * HH + j]      = emb_table[t * H2 + j];       // shape_emb half
    lut[combo * HH + H2 + j] = acc + b[t * H2 + j];         // size_emb half
}

__global__ __launch_bounds__(256) void clique_gather(
        const i32x2* __restrict__ attr,    // (N,2) int32 as i32x2 per row
        const f32x4* __restrict__ lut,     // 16 rows x 32 float4 (8 KB)
        f32x4* __restrict__ out,           // N x 32 float4
        int nrows) {
    __shared__ f32x4 slut[16 * 32];           // 8 KB
    __shared__ int scombo[ROWS_PER_BLOCK];    // 4 KB (prescaled by 32)
    const int tid = threadIdx.x;

    // Stage LUT into LDS: 512 float4 across 256 threads.
    slut[tid]       = lut[tid];
    slut[tid + 256] = lut[tid + 256];

    const int r0   = blockIdx.x * ROWS_PER_BLOCK;
    const int rcnt = min(nrows - r0, ROWS_PER_BLOCK);

    // Stage combo indices: one coalesced i32x2 load per row, once.
    // Prescale by 32 (slut row stride in float4s) to save a VALU op/iter.
    // nt load: attr is read exactly once — keep it out of L2/L3.
    for (int i = tid; i < rcnt; i += 256) {
        i32x2 td = __builtin_nontemporal_load(&attr[r0 + i]);
        scombo[i] = (((td.x & 3) << 2) | (td.y & 3)) << 5;
    }
    __syncthreads();

    // Pure store loop: LDS read + 16B coalesced non-temporal store.
    // c4 = flat & 31 is loop-invariant because stride 256 == 0 (mod 32).
    const int total = rcnt * 32;              // float4s this block emits
    f32x4* obase = out + (size_t)r0 * 32;
    const int c4 = tid & 31;                  // this thread's float4 column
#pragma unroll 4
    for (int flat = tid; flat < total; flat += 256) {
        int rl = flat >> 5;                   // local row
        f32x4 v = slut[scombo[rl] + c4];
        __builtin_nontemporal_store(v, &obase[flat]);
    }
}

extern "C" void kernel_launch(void* const* d_in, const int* in_sizes, int n_in,
                              void* d_out, int out_size, void* d_ws, size_t ws_size,
                              hipStream_t stream) {
    const int*   attr = (const int*)d_in[0];     // (N,2) int32
    const float* emb  = (const float*)d_in[1];   // (4,64) f32
    const float* W    = (const float*)d_in[2];   // (4,32,64) f32
    const float* b    = (const float*)d_in[3];   // (4,64) f32
    float* out = (float*)d_out;
    float* lut = (float*)d_ws;                   // needs 16*128*4 = 8 KB

    int n = in_sizes[0] / 2;                     // number of rows
    clique_build_lut<<<16, 64, 0, stream>>>(emb, W, b, lut);

    int blocks = (n + ROWS_PER_BLOCK - 1) / ROWS_PER_BLOCK;
    clique_gather<<<blocks, 256, 0, stream>>>(
        (const i32x2*)attr, (const f32x4*)lut, (f32x4*)out, n);
}

// Round 5
// 510.100 us; speedup vs baseline: 1.0039x; 1.0039x over previous
//
#include <hip/hip_runtime.h>

// CliqueEncoder: N=1e6 rows, H=128, RBF=32, H2=64, NUM_TYPES=4.
// t,d in [0,4) -> only 16 distinct 128-float output rows.
// R4: single fused kernel. Each block computes the 16x128 LUT itself
// (~1 us: 128 expf -> LDS basis, then 8 dot-32 per thread), then the
// proven store loop (ds_read_b128 + nt global_store_dwordx4).
// Removes: K1 launch node, d_ws round-trip, inter-kernel dependency.
// Evidence so far (R4 profile): harness poison-fill (2 GB, 325 us, 6.29 TB/s,
// FETCH~0) dominates the judged window; plain full-line stores do NOT
// write-allocate on gfx950. Our kernels are <321 us total (below top-5 cut).
// Floor for our portion: 520 MB / 6.29 TB/s ~= 83 us.

typedef float f32x4 __attribute__((ext_vector_type(4)));
typedef int   i32x4 __attribute__((ext_vector_type(4)));

#define HH 128
#define H2 64
#define RBF 32
#define MAX_DIST 20.0f
#define ROWS_PER_BLOCK 1024

__global__ __launch_bounds__(256) void clique_fused(
        const int*   __restrict__ attr,    // (N,2) int32
        const float* __restrict__ emb,     // (4,64) f32
        const float* __restrict__ W,       // (4,32,64) f32
        const float* __restrict__ b,       // (4,64) f32
        f32x4*       __restrict__ out,     // N x 32 float4
        int nrows) {
    __shared__ f32x4 slut[16 * 32];           // 8 KB  (16 combos x 128 f32)
    __shared__ float sbasis[4 * RBF];         // 512 B (basis[dval][k])
    __shared__ int   scombo[ROWS_PER_BLOCK];  // 4 KB  (prescaled by 32)
    const int tid = threadIdx.x;

    const int r0   = blockIdx.x * ROWS_PER_BLOCK;
    const int rcnt = min(nrows - r0, ROWS_PER_BLOCK);

    // ---- Phase A: stage attr (dwordx4 = 2 rows/load) + gaussian basis ----
    const i32x4* attr4 = (const i32x4*)(attr + (size_t)r0 * 2);
    const int npairs = (rcnt + 1) >> 1;
    for (int i = tid; i < npairs; i += 256) {
        i32x4 v = __builtin_nontemporal_load(&attr4[i]);
        scombo[2 * i] = (((v.x & 3) << 2) | (v.y & 3)) << 5;
        if (2 * i + 1 < rcnt)
            scombo[2 * i + 1] = (((v.z & 3) << 2) | (v.w & 3)) << 5;
    }
    if (tid < 4 * RBF) {                       // 128 threads, wave-uniform-ish
        const float stdv = MAX_DIST / (float)(RBF - 1);
        int dval = tid >> 5;                   // 0..3
        int k    = tid & 31;                   // 0..31
        float c  = MAX_DIST * (float)k / (float)(RBF - 1);
        float diff = (float)dval - c;
        sbasis[tid] = expf(-0.5f * diff * diff / (stdv * stdv));
    }
    __syncthreads();

    // ---- Phase B: build 16x128 LUT in LDS (8 entries/thread) ----
    // tid -> (j = tid & 127, cg = tid >> 7); branches are wave-uniform.
    {
        int j  = tid & 127;
        int cg = tid >> 7;                     // combo group: 0..7 or 8..15
        float* slutf = (float*)slut;
        if (j < H2) {
#pragma unroll
            for (int cc = 0; cc < 8; ++cc) {
                int c = cg * 8 + cc;
                int t = c >> 2;
                slutf[c * HH + j] = emb[t * H2 + j];        // shape_emb half
            }
        } else {
            int jj = j - H2;
#pragma unroll
            for (int cc = 0; cc < 8; ++cc) {
                int c  = cg * 8 + cc;
                int t  = c >> 2;
                int dv = c & 3;
                float acc = 0.0f;
#pragma unroll
                for (int k = 0; k < RBF; ++k)
                    acc += sbasis[dv * RBF + k] * W[(t * RBF + k) * H2 + jj];
                slutf[c * HH + j] = acc + b[t * H2 + jj];   // size_emb half
            }
        }
    }
    __syncthreads();

    // ---- Phase C: pure store loop (unchanged, proven) ----
    const int total = rcnt * 32;              // float4s this block emits
    f32x4* obase = out + (size_t)r0 * 32;
    const int c4 = tid & 31;                  // loop-invariant f4 column
#pragma unroll 4
    for (int flat = tid; flat < total; flat += 256) {
        int rl = flat >> 5;                   // local row
        f32x4 v = slut[scombo[rl] + c4];
        __builtin_nontemporal_store(v, &obase[flat]);
    }
}

extern "C" void kernel_launch(void* const* d_in, const int* in_sizes, int n_in,
                              void* d_out, int out_size, void* d_ws, size_t ws_size,
                              hipStream_t stream) {
    const int*   attr = (const int*)d_in[0];     // (N,2) int32
    const float* emb  = (const float*)d_in[1];   // (4,64) f32
    const float* W    = (const float*)d_in[2];   // (4,32,64) f32
    const float* b    = (const float*)d_in[3];   // (4,64) f32
    float* out = (float*)d_out;
    (void)d_ws; (void)ws_size;

    int n = in_sizes[0] / 2;                     // number of rows
    int blocks = (n + ROWS_PER_BLOCK - 1) / ROWS_PER_BLOCK;
    clique_fused<<<blocks, 256, 0, stream>>>(
        attr, emb, W, b, (f32x4*)out, n);
}